// Round 14
// baseline (300.893 us; speedup 1.0000x reference)
//
#include <hip/hip_runtime.h>

#define NE 100000   // edges
#define NN 50000    // nodes
#define NT 1563     // ceil(NE/64)
#define GRID_QKV 512

typedef short short8 __attribute__((ext_vector_type(8)));
typedef float f32x4 __attribute__((ext_vector_type(4)));
typedef unsigned short ushort;
typedef unsigned int uint;

__device__ inline ushort f2bf(float f) {
    unsigned int u = __float_as_uint(f);
    u += 0x7FFFu + ((u >> 16) & 1u);
    return (ushort)(u >> 16);
}
__device__ inline float bf2f(ushort u) {
    return __uint_as_float((unsigned int)u << 16);
}

__device__ inline short8 pack_bf8(float4 a, float4 b) {
    short8 r;
    r[0] = (short)f2bf(a.x); r[1] = (short)f2bf(a.y);
    r[2] = (short)f2bf(a.z); r[3] = (short)f2bf(a.w);
    r[4] = (short)f2bf(b.x); r[5] = (short)f2bf(b.y);
    r[6] = (short)f2bf(b.z); r[7] = (short)f2bf(b.w);
    return r;
}

// ---------------------------------------------------------------------------
// Prep: pack both layers' QKV (72 frags) + Wo (8 frags) into bf16 fragment
// order: wf[((s*12+t)*64+lane)*8+j] = W[k=32s+(lane>>4)*8+j][n=16t+(lane&15)]
// ---------------------------------------------------------------------------
__device__ inline void pack_qkv_slot(int slot, const float* Wq, const float* Wk,
                                     const float* Wv, ushort* wf)
{
    int lane = slot & 63;
    int st = slot >> 6;
    int s = st / 12, t = st % 12;
    int n = t * 16 + (lane & 15);
    int kb = s * 32 + (lane >> 4) * 8;
    const float* w = (n < 64) ? Wq : (n < 128) ? Wk : Wv;
    int nn = n & 63;
    #pragma unroll
    for (int j = 0; j < 8; ++j)
        wf[(size_t)slot * 8 + j] = f2bf(w[(size_t)(kb + j) * 64 + nn]);
}

__device__ inline void pack_wo_slot(int slot, const float* Wo, ushort* wf)
{
    int lane = slot & 63;
    int st = slot >> 6;
    int s = st / 4, t = st % 4;
    int n = t * 16 + (lane & 15);
    int kb = s * 32 + (lane >> 4) * 8;
    #pragma unroll
    for (int j = 0; j < 8; ++j)
        wf[(size_t)slot * 8 + j] = f2bf(Wo[(size_t)(kb + j) * 64 + n]);
}

__global__ __launch_bounds__(256) void prep_all(
    const float* __restrict__ l1Wq, const float* __restrict__ l1Wk,
    const float* __restrict__ l1Wv, const float* __restrict__ l1Wo,
    const float* __restrict__ l2Wq, const float* __restrict__ l2Wk,
    const float* __restrict__ l2Wv, const float* __restrict__ l2Wo,
    ushort* __restrict__ wf1, ushort* __restrict__ wf2,
    ushort* __restrict__ wo1, ushort* __restrict__ wo2)
{
    int idx = blockIdx.x * 256 + threadIdx.x;
    if (idx < 4608)            pack_qkv_slot(idx,         l1Wq, l1Wk, l1Wv, wf1);
    else if (idx < 9216)       pack_qkv_slot(idx - 4608,  l2Wq, l2Wk, l2Wv, wf2);
    else if (idx < 9728)       pack_wo_slot (idx - 9216,  l1Wo, wo1);
    else if (idx < 10240)      pack_wo_slot (idx - 9728,  l2Wo, wo2);
}

#define MFMA_B16(a, b, c) c = __builtin_amdgcn_mfma_f32_16x16x32_bf16(a, b, c, 0, 0, 0)
#define GLP const __attribute__((address_space(1))) uint*
#define LDP __attribute__((address_space(3))) uint*

// ---------------------------------------------------------------------------
// QKV GEMM — persistent + SOFTWARE-PIPELINED tiles.
// 512 blocks, 2/CU (144 KB LDS). B panel (72 KB) staged once. Tile loop
// processes tiles in pairs with two named prefetch sets (A/B): tile t+1's
// eidx + 12 float4 loads are issued before tile t's K-loop, hiding the
// 2-deep gather chain under ~1500 cy of MFMA/ds_read work.
// ---------------------------------------------------------------------------
#define PRE(S, tl) do {                                                        \
    const int e_  = (tl) * 64 + w * 16 + r;                                    \
    const int ec_ = (e_ < NE) ? e_ : NE - 1;                                   \
    const int sa_ = eidx[ec_];                                                 \
    const int da_ = eidx[NE + ec_];                                            \
    const float* p0_ = efin  + (size_t)ec_ * 64 + koff;                        \
    const float* p1_ = nodef + (size_t)sa_ * 64 + koff;                        \
    const float* p2_ = nodef + (size_t)da_ * 64 + koff;                        \
    f##S##_0  = *(const float4*)(p0_);      f##S##_1  = *(const float4*)(p0_ + 4);  \
    f##S##_2  = *(const float4*)(p0_ + 32); f##S##_3  = *(const float4*)(p0_ + 36); \
    f##S##_4  = *(const float4*)(p1_);      f##S##_5  = *(const float4*)(p1_ + 4);  \
    f##S##_6  = *(const float4*)(p1_ + 32); f##S##_7  = *(const float4*)(p1_ + 36); \
    f##S##_8  = *(const float4*)(p2_);      f##S##_9  = *(const float4*)(p2_ + 4);  \
    f##S##_10 = *(const float4*)(p2_ + 32); f##S##_11 = *(const float4*)(p2_ + 36); \
} while (0)

#define K12(s, Areg) do {                                                      \
    const char* lb_ = ldsb + (size_t)(s) * 12288 + (size_t)l * 16;             \
    MFMA_B16(Areg, *(const short8*)(lb_ +     0), c0);                         \
    MFMA_B16(Areg, *(const short8*)(lb_ +  1024), c1);                         \
    MFMA_B16(Areg, *(const short8*)(lb_ +  2048), c2);                         \
    MFMA_B16(Areg, *(const short8*)(lb_ +  3072), c3);                         \
    MFMA_B16(Areg, *(const short8*)(lb_ +  4096), c4);                         \
    MFMA_B16(Areg, *(const short8*)(lb_ +  5120), c5);                         \
    MFMA_B16(Areg, *(const short8*)(lb_ +  6144), c6);                         \
    MFMA_B16(Areg, *(const short8*)(lb_ +  7168), c7);                         \
    MFMA_B16(Areg, *(const short8*)(lb_ +  8192), c8);                         \
    MFMA_B16(Areg, *(const short8*)(lb_ +  9216), c9);                         \
    MFMA_B16(Areg, *(const short8*)(lb_ + 10240), c10);                        \
    MFMA_B16(Areg, *(const short8*)(lb_ + 11264), c11);                        \
} while (0)

#define STT(creg, dstp, coloff) do {                                           \
    ushort* dp_ = (dstp) + (coloff) + r;                                       \
    if (orow_ + 0 < NE) dp_[(size_t)(orow_ + 0) * 64] = f2bf(creg[0]);         \
    if (orow_ + 1 < NE) dp_[(size_t)(orow_ + 1) * 64] = f2bf(creg[1]);         \
    if (orow_ + 2 < NE) dp_[(size_t)(orow_ + 2) * 64] = f2bf(creg[2]);         \
    if (orow_ + 3 < NE) dp_[(size_t)(orow_ + 3) * 64] = f2bf(creg[3]);         \
} while (0)

#define COMP(S, tl) do {                                                       \
    f32x4 c0 = (f32x4)(0.f), c1 = (f32x4)(0.f), c2  = (f32x4)(0.f);            \
    f32x4 c3 = (f32x4)(0.f), c4 = (f32x4)(0.f), c5  = (f32x4)(0.f);            \
    f32x4 c6 = (f32x4)(0.f), c7 = (f32x4)(0.f), c8  = (f32x4)(0.f);            \
    f32x4 c9 = (f32x4)(0.f), c10 = (f32x4)(0.f), c11 = (f32x4)(0.f);           \
    short8 A_;                                                                 \
    A_ = pack_bf8(f##S##_0,  f##S##_1);  K12(0, A_);                           \
    A_ = pack_bf8(f##S##_2,  f##S##_3);  K12(1, A_);                           \
    A_ = pack_bf8(f##S##_4,  f##S##_5);  K12(2, A_);                           \
    A_ = pack_bf8(f##S##_6,  f##S##_7);  K12(3, A_);                           \
    A_ = pack_bf8(f##S##_8,  f##S##_9);  K12(4, A_);                           \
    A_ = pack_bf8(f##S##_10, f##S##_11); K12(5, A_);                           \
    const int orow_ = (tl) * 64 + w * 16 + kg * 4;                             \
    STT(c0,  qo,  0); STT(c1,  qo, 16); STT(c2,  qo, 32); STT(c3,  qo, 48);    \
    STT(c4,  ko,  0); STT(c5,  ko, 16); STT(c6,  ko, 32); STT(c7,  ko, 48);    \
    STT(c8,  vo,  0); STT(c9,  vo, 16); STT(c10, vo, 32); STT(c11, vo, 48);    \
} while (0)

__global__ __launch_bounds__(256, 2) void qkv_mfma(
    const float* __restrict__ efin, const float* __restrict__ nodef,
    const int* __restrict__ eidx, const ushort* __restrict__ wfrag,
    ushort* __restrict__ qo, ushort* __restrict__ ko, ushort* __restrict__ vo)
{
    __shared__ __align__(1024) char ldsb[72 * 1024];

    const int tid = threadIdx.x;
    const int l   = tid & 63;
    const int w   = tid >> 6;
    const int r   = l & 15;
    const int kg  = l >> 4;
    const int koff = kg * 8;
    const int bid = blockIdx.x;

    // ---- stage all 72 B fragments once ----
    #pragma unroll 1
    for (int i = 0; i < 18; ++i) {
        const int fr = w * 18 + i;
        __builtin_amdgcn_global_load_lds(
            (GLP)((const char*)wfrag + (size_t)fr * 1024 + (size_t)l * 16),
            (LDP)(ldsb + (size_t)fr * 1024 + (size_t)l * 16), 16, 0, 0);
    }

    // ---- pipelined tile loop (2 named prefetch sets) ----
    float4 fA_0, fA_1, fA_2, fA_3, fA_4, fA_5, fA_6, fA_7, fA_8, fA_9, fA_10, fA_11;
    float4 fB_0, fB_1, fB_2, fB_3, fB_4, fB_5, fB_6, fB_7, fB_8, fB_9, fB_10, fB_11;

    PRE(A, bid);                 // prefetch first tile while B stages
    __syncthreads();             // B panel ready

    #pragma unroll 1
    for (int i = 0; ; i += 2) {
        const int tA = bid + i * GRID_QKV;
        const int tB = tA + GRID_QKV;
        if (tB < NT) {
            PRE(B, tB);
            COMP(A, tA);
            const int tC = tB + GRID_QKV;
            if (tC < NT) {
                PRE(A, tC);
                COMP(B, tB);
            } else {
                COMP(B, tB);
                break;
            }
        } else {
            COMP(A, tA);
            break;
        }
    }
}

// ---------------------------------------------------------------------------
// Attention: one wave per dst edge. lane = half*32 + h*8 + dd.
// ---------------------------------------------------------------------------
__global__ __launch_bounds__(256) void attn_kernel(
    const ushort* __restrict__ q, const ushort* __restrict__ kbuf,
    const ushort* __restrict__ vbuf, const int* __restrict__ adj_src,
    ushort* __restrict__ ao)
{
    const int wid  = (blockIdx.x * 256 + threadIdx.x) >> 6;
    const int lane = threadIdx.x & 63;
    if (wid >= NE) return;
    const int e    = wid;
    const int half = lane >> 5;
    const int l32  = lane & 31;

    const int4 nb = *(const int4*)(adj_src + e * 8 + half * 4);
    const int nbr0 = nb.x, nbr1 = nb.y, nbr2 = nb.z, nbr3 = nb.w;

    ushort2 qu = *(const ushort2*)(q + (size_t)e * 64 + l32 * 2);
    const float q0 = bf2f(qu.x), q1 = bf2f(qu.y);

    ushort2 ku0 = *(const ushort2*)(kbuf + (size_t)nbr0 * 64 + l32 * 2);
    ushort2 ku1 = *(const ushort2*)(kbuf + (size_t)nbr1 * 64 + l32 * 2);
    ushort2 ku2 = *(const ushort2*)(kbuf + (size_t)nbr2 * 64 + l32 * 2);
    ushort2 ku3 = *(const ushort2*)(kbuf + (size_t)nbr3 * 64 + l32 * 2);
    ushort2 vu0 = *(const ushort2*)(vbuf + (size_t)nbr0 * 64 + l32 * 2);
    ushort2 vu1 = *(const ushort2*)(vbuf + (size_t)nbr1 * 64 + l32 * 2);
    ushort2 vu2 = *(const ushort2*)(vbuf + (size_t)nbr2 * 64 + l32 * 2);
    ushort2 vu3 = *(const ushort2*)(vbuf + (size_t)nbr3 * 64 + l32 * 2);

    float s0 = q0 * bf2f(ku0.x) + q1 * bf2f(ku0.y);
    float s1 = q0 * bf2f(ku1.x) + q1 * bf2f(ku1.y);
    float s2 = q0 * bf2f(ku2.x) + q1 * bf2f(ku2.y);
    float s3 = q0 * bf2f(ku3.x) + q1 * bf2f(ku3.y);
    s0 += __shfl_xor(s0, 1); s0 += __shfl_xor(s0, 2); s0 += __shfl_xor(s0, 4);
    s1 += __shfl_xor(s1, 1); s1 += __shfl_xor(s1, 2); s1 += __shfl_xor(s1, 4);
    s2 += __shfl_xor(s2, 1); s2 += __shfl_xor(s2, 2); s2 += __shfl_xor(s2, 4);
    s3 += __shfl_xor(s3, 1); s3 += __shfl_xor(s3, 2); s3 += __shfl_xor(s3, 4);
    s0 *= 0.25f; s1 *= 0.25f; s2 *= 0.25f; s3 *= 0.25f;

    float m = fmaxf(fmaxf(s0, s1), fmaxf(s2, s3));
    m = fmaxf(m, __shfl_xor(m, 32));
    float w0 = __expf(s0 - m), w1 = __expf(s1 - m);
    float w2 = __expf(s2 - m), w3 = __expf(s3 - m);
    float den = w0 + w1 + w2 + w3;
    den += __shfl_xor(den, 32);
    const float inv = 1.f / den;

    float ox = 0.f, oy = 0.f;
    ox = fmaf(w0, bf2f(vu0.x), ox); oy = fmaf(w0, bf2f(vu0.y), oy);
    ox = fmaf(w1, bf2f(vu1.x), ox); oy = fmaf(w1, bf2f(vu1.y), oy);
    ox = fmaf(w2, bf2f(vu2.x), ox); oy = fmaf(w2, bf2f(vu2.y), oy);
    ox = fmaf(w3, bf2f(vu3.x), ox); oy = fmaf(w3, bf2f(vu3.y), oy);
    ox = (ox + __shfl_xor(ox, 32)) * inv;
    oy = (oy + __shfl_xor(oy, 32)) * inv;

    if (lane < 32) {
        ushort2 o;
        o.x = f2bf(ox);
        o.y = f2bf(oy);
        *(ushort2*)(ao + (size_t)e * 64 + l32 * 2) = o;
    }
}

// ---------------------------------------------------------------------------
// Wo GEMM via MFMA + fused residual: out = ef_in + attn(bf16) @ Wo.
// ---------------------------------------------------------------------------
__global__ __launch_bounds__(256) void wo_mfma(
    const float* __restrict__ ef_in, const ushort* __restrict__ attn,
    const ushort* __restrict__ wofrag, float* __restrict__ efo)
{
    const int wave = threadIdx.x >> 6;
    const int lane = threadIdx.x & 63;
    const int r  = lane & 15;
    const int kg = lane >> 4;
    const int e0 = blockIdx.x * 64 + wave * 16;
    const int e  = e0 + r;
    const int ec = (e < NE) ? e : NE - 1;

    short8 af0 = *(const short8*)(attn + (size_t)ec * 64 + kg * 8);
    short8 af1 = *(const short8*)(attn + (size_t)ec * 64 + 32 + kg * 8);

    const char* wf = (const char*)wofrag + (size_t)lane * 16;
    f32x4 d0 = (f32x4)(0.f), d1 = (f32x4)(0.f), d2 = (f32x4)(0.f), d3 = (f32x4)(0.f);
    short8 g0 = *(const short8*)(wf + 0 * 1024);
    short8 g1 = *(const short8*)(wf + 1 * 1024);
    short8 g2 = *(const short8*)(wf + 2 * 1024);
    short8 g3 = *(const short8*)(wf + 3 * 1024);
    MFMA_B16(af0, g0, d0); MFMA_B16(af0, g1, d1);
    MFMA_B16(af0, g2, d2); MFMA_B16(af0, g3, d3);
    g0 = *(const short8*)(wf + 4 * 1024);
    g1 = *(const short8*)(wf + 5 * 1024);
    g2 = *(const short8*)(wf + 6 * 1024);
    g3 = *(const short8*)(wf + 7 * 1024);
    MFMA_B16(af1, g0, d0); MFMA_B16(af1, g1, d1);
    MFMA_B16(af1, g2, d2); MFMA_B16(af1, g3, d3);

    const int orow = e0 + kg * 4;
    #pragma unroll
    for (int t = 0; t < 4; ++t) {
        const f32x4 dd = (t == 0) ? d0 : (t == 1) ? d1 : (t == 2) ? d2 : d3;
        const int c = t * 16 + r;
        #pragma unroll
        for (int j = 0; j < 4; ++j) {
            int row = orow + j;
            if (row < NE) {
                size_t off = (size_t)row * 64 + c;
                efo[off] = dd[j] + ef_in[off];
            }
        }
    }
}

// ---------------------------------------------------------------------------
extern "C" void kernel_launch(void* const* d_in, const int* in_sizes, int n_in,
                              void* d_out, int out_size, void* d_ws, size_t ws_size,
                              hipStream_t stream)
{
    const float* nodef   = (const float*)d_in[0];
    const float* ef      = (const float*)d_in[1];
    const int*   eidx    = (const int*)d_in[2];   // [2,E]
    const int*   adj_src = (const int*)d_in[4];
    const float* l1Wq = (const float*)d_in[6];
    const float* l1Wk = (const float*)d_in[7];
    const float* l1Wv = (const float*)d_in[8];
    const float* l1Wo = (const float*)d_in[9];
    const float* l2Wq = (const float*)d_in[10];
    const float* l2Wk = (const float*)d_in[11];
    const float* l2Wv = (const float*)d_in[12];
    const float* l2Wo = (const float*)d_in[13];

    ushort* q   = (ushort*)d_ws;                 // [E,64] bf16
    ushort* k   = q   + (size_t)NE * 64;
    ushort* v   = k   + (size_t)NE * 64;
    ushort* ao  = v   + (size_t)NE * 64;
    ushort* wf1 = ao  + (size_t)NE * 64;         // 36864 ushorts each
    ushort* wf2 = wf1 + 36864;
    ushort* wo1 = wf2 + 36864;                   // 4096 each
    ushort* wo2 = wo1 + 4096;
    float* out = (float*)d_out;

    dim3 blk(256);
    const int ga = (NE + 3) / 4;      // 25000
    const int gw = (NE + 63) / 64;    // 1563

    prep_all<<<40, blk, 0, stream>>>(l1Wq, l1Wk, l1Wv, l1Wo,
                                     l2Wq, l2Wk, l2Wv, l2Wo,
                                     wf1, wf2, wo1, wo2);

    // ---- layer 1 ----
    qkv_mfma<<<GRID_QKV, blk, 0, stream>>>(ef, nodef, eidx, wf1, q, k, v);
    attn_kernel<<<ga, blk, 0, stream>>>(q, k, v, adj_src, ao);
    wo_mfma<<<gw, blk, 0, stream>>>(ef, ao, wo1, out);
    // ---- layer 2 ----
    qkv_mfma<<<GRID_QKV, blk, 0, stream>>>(out, nodef, eidx, wf2, q, k, v);
    attn_kernel<<<ga, blk, 0, stream>>>(q, k, v, adj_src, ao);
    wo_mfma<<<gw, blk, 0, stream>>>(out, ao, wo2, out);
}